// Round 8
// baseline (327.324 us; speedup 1.0000x reference)
//
#include <hip/hip_runtime.h>
#include <hip/hip_bf16.h>
#include <stdint.h>

// Problem constants: B=2, S=2048, H=2048, NH=32, HD=64
#define S_LEN 2048
#define NHEAD 32
#define HDIM  64

using bf16x8 = __attribute__((ext_vector_type(8))) short;
using f32x4  = __attribute__((ext_vector_type(4))) float;
using f32x16 = __attribute__((ext_vector_type(16))) float;

__device__ __forceinline__ uint16_t f2bf(float f) {
  union { float f; uint32_t u; } c; c.f = f;
  uint32_t u = c.u;
  return (uint16_t)((u + 0x7FFFu + ((u >> 16) & 1u)) >> 16);
}

__device__ __forceinline__ void load_lds16(const void* g, void* l) {
  __builtin_amdgcn_global_load_lds(
      (const __attribute__((address_space(1))) void*)g,
      (__attribute__((address_space(3))) void*)l, 16, 0, 0);
}

__device__ __forceinline__ f32x16 mfma32(bf16x8 a, bf16x8 b, f32x16 c) {
  return __builtin_amdgcn_mfma_f32_32x32x16_bf16(a, b, c, 0, 0, 0);
}

__device__ __forceinline__ uint32_t cvtpk(float lo, float hi_) {
  uint32_t d;
  asm("v_cvt_pk_bf16_f32 %0, %1, %2" : "=v"(d) : "v"(lo), "v"(hi_));
  return d;
}
__device__ __forceinline__ void plswap(uint32_t& a, uint32_t& b) {
  asm volatile("v_permlane32_swap_b32 %0, %1" : "+v"(a), "+v"(b));
}

// ---------------- batched fp32 -> bf16 conversion ----------------
__global__ __launch_bounds__(256) void conv_batch(
    const float* __restrict__ X, const float* __restrict__ Wq,
    const float* __restrict__ Wk, const float* __restrict__ Wv,
    uint16_t* __restrict__ Xbf, uint16_t* __restrict__ Wqk,
    uint16_t* __restrict__ Wvb) {
  int i = blockIdx.x * 256 + threadIdx.x;  // total 5242880
  const float* src; uint16_t* dst; int o;
  if (i < 2097152)      { src = X;  dst = Xbf;           o = i; }
  else if (i < 3145728) { src = Wq; dst = Wqk;           o = i - 2097152; }
  else if (i < 4194304) { src = Wk; dst = Wqk + 4194304; o = i - 3145728; }
  else                  { src = Wv; dst = Wvb;           o = i - 4194304; }
  float4 v = ((const float4*)src)[o];
  uint64_t packed = (uint64_t)f2bf(v.x) | ((uint64_t)f2bf(v.y) << 16) |
                    ((uint64_t)f2bf(v.z) << 32) | ((uint64_t)f2bf(v.w) << 48);
  ((uint64_t*)dst)[o] = packed;
}

__global__ __launch_bounds__(256) void conv_f32_bf16(
    const float* __restrict__ in, uint16_t* __restrict__ out, int n4) {
  int i = blockIdx.x * 256 + threadIdx.x;
  if (i < n4) {
    float4 v = ((const float4*)in)[i];
    uint64_t packed = (uint64_t)f2bf(v.x) | ((uint64_t)f2bf(v.y) << 16) |
                      ((uint64_t)f2bf(v.z) << 32) | ((uint64_t)f2bf(v.w) << 48);
    ((uint64_t*)out)[i] = packed;
  }
}

// ---------------- fused QK GEMM: 256x128, BK=32, A-in-LDS, B-in-regs ------
// B-fragments load straight from global (L2/L3-hot) one tile ahead into
// registers -> LDS fragment reads drop 12KB -> 8KB per wave-tile, staging
// writes halve. A staged via 3-buf global_load_lds; counted vmcnt(4)
// (leave newest A-stage in flight), single barrier per tile.
__global__ __launch_bounds__(256, 2) void gemm_qk(
    const uint16_t* __restrict__ A, const uint16_t* __restrict__ Bw,
    uint16_t* __restrict__ Qo, uint16_t* __restrict__ Ko, float qscale) {
  __shared__ __align__(16) char smem[3][16384];  // A tiles only, 48 KB
  const int t = threadIdx.x;
  const int lane = t & 63, w = t >> 6;
  const int lrow = lane & 15, lgrp = lane >> 4;
  const int wm = (w >> 1) * 128, wn = (w & 1) * 64;
  const int id = blockIdx.x;                  // 512 blocks, 2/CU
  const int xcd = id & 7, loc = id >> 3;
  const int bm = (loc & 15) * 256;
  const int bn = (xcd * 4 + (loc >> 4)) * 128;
  constexpr int NT = 2048 / 32;

  const f32x4 zero4 = {0.f, 0.f, 0.f, 0.f};
  f32x4 acc[8][4];
#pragma unroll
  for (int mi = 0; mi < 8; ++mi)
#pragma unroll
    for (int ni = 0; ni < 4; ++ni) acc[mi][ni] = zero4;

  auto stageA = [&](char* buf, int kt) {
#pragma unroll
    for (int j = 0; j < 4; ++j) {
      const int s = t + j * 256;
      const int row = s >> 2;
      const int sc = (s & 3) ^ ((row >> 1) & 3);
      load_lds16(A + (size_t)(bm + row) * 2048 + kt + sc * 8,
                 buf + j * 4096 + w * 1024);
    }
  };
  auto ldfA = [&](const char* buf, int mi) -> bf16x8 {
    const int row = wm + mi * 16 + lrow;
    return *(const bf16x8*)(buf + row * 64 +
                            ((lgrp ^ ((row >> 1) & 3)) << 4));
  };
  const uint16_t* Bbase = Bw + (size_t)(bn + wn + lrow) * 2048 + lgrp * 8;

  bf16x8 bA[4], bB[4];
  // prologue: A(0), B(0)->bA, A(1)   (queue: A0[4] B0[4] A1[4])
  stageA(smem[0], 0);
#pragma unroll
  for (int ni = 0; ni < 4; ++ni) bA[ni] = *(const bf16x8*)(Bbase + ni * 32768);
  stageA(smem[1], 32);

#define QK_TILE(KT, BCUR, BNEXT)                                             \
  {                                                                          \
    if ((KT) < NT - 1) asm volatile("s_waitcnt vmcnt(4)" ::: "memory");      \
    else               asm volatile("s_waitcnt vmcnt(0)" ::: "memory");      \
    __builtin_amdgcn_s_barrier();                                            \
    if ((KT) + 1 < NT) {                                                     \
      _Pragma("unroll")                                                      \
      for (int ni = 0; ni < 4; ++ni)                                         \
        BNEXT[ni] = *(const bf16x8*)(Bbase + ni * 32768 + ((KT) + 1) * 32);  \
    }                                                                        \
    if ((KT) + 2 < NT) stageA(smem[((KT) + 2) % 3], ((KT) + 2) * 32);        \
    const char* cur = smem[(KT) % 3];                                        \
    bf16x8 aF[8];                                                            \
    _Pragma("unroll")                                                        \
    for (int mi = 0; mi < 8; ++mi) aF[mi] = ldfA(cur, mi);                   \
    _Pragma("unroll")                                                        \
    for (int mi = 0; mi < 8; ++mi)                                           \
      _Pragma("unroll")                                                      \
      for (int ni = 0; ni < 4; ++ni)                                         \
        acc[mi][ni] = __builtin_amdgcn_mfma_f32_16x16x32_bf16(               \
            aF[mi], BCUR[ni], acc[mi][ni], 0, 0, 0);                         \
  }

  for (int kt = 0; kt < NT; kt += 2) {
    QK_TILE(kt, bA, bB);
    QK_TILE(kt + 1, bB, bA);
  }
#undef QK_TILE

  // epilogue: row = lgrp*4+r, col = lrow (m89 layout)
  const bool isQ = (bn < 2048);
#pragma unroll
  for (int mi = 0; mi < 8; ++mi) {
#pragma unroll
    for (int ni = 0; ni < 4; ++ni) {
      const int n = bn + wn + ni * 16 + lrow;
      const int n2 = isQ ? n : (n - 2048);
      const int h = n2 >> 6, d = n2 & 63;
#pragma unroll
      for (int r = 0; r < 4; ++r) {
        const int m = bm + wm + mi * 16 + lgrp * 4 + r;
        const int b = m >> 11, s = m & 2047;
        const size_t off = (((size_t)(b * NHEAD + h) * S_LEN + s) * HDIM) + d;
        if (isQ) Qo[off] = f2bf(acc[mi][ni][r] * qscale);
        else     Ko[off] = f2bf(acc[mi][ni][r]);
      }
    }
  }
}

// ---------------- NT GEMM 128^2, BK=32, A-in-LDS, B-in-regs ----------------
// MODE 1: store bf16 [B,NH,HD,S] from m=(h,d), n=(b,s)
// MODE 2: store fp32 row-major [M][N]
template<int MODE>
__global__ __launch_bounds__(256, 2) void gemm_nt(
    const uint16_t* __restrict__ A, const uint16_t* __restrict__ B,
    void* __restrict__ C, int M, int N, int K, float scale) {
  __shared__ __align__(16) char smem[3][8192];  // A tiles only, 24 KB

  const int t = threadIdx.x;
  const int lane = t & 63, w = t >> 6;
  const int lrow = lane & 15, lgrp = lane >> 4;
  const int bm = blockIdx.y * 128, bn = blockIdx.x * 128;
  const int wm = (w >> 1) * 64, wn = (w & 1) * 64;
  const int NT = K / 32;

  const f32x4 zero4 = {0.f, 0.f, 0.f, 0.f};
  f32x4 acc[4][4];
#pragma unroll
  for (int mi = 0; mi < 4; ++mi)
#pragma unroll
    for (int ni = 0; ni < 4; ++ni) acc[mi][ni] = zero4;

  auto stageA = [&](char* buf, int kt) {
#pragma unroll
    for (int j = 0; j < 2; ++j) {
      const int s = t + j * 256;
      const int row = s >> 2;
      const int sc = (s & 3) ^ ((row >> 1) & 3);
      load_lds16(A + (size_t)(bm + row) * K + kt + sc * 8,
                 buf + j * 4096 + w * 1024);
    }
  };
  auto ldfA = [&](const char* buf, int mi) -> bf16x8 {
    const int row = wm + mi * 16 + lrow;
    return *(const bf16x8*)(buf + row * 64 +
                            ((lgrp ^ ((row >> 1) & 3)) << 4));
  };
  const uint16_t* Bbase = B + (size_t)(bn + wn + lrow) * K + lgrp * 8;
  const size_t bstep = (size_t)16 * K;  // 16 rows per ni step

  bf16x8 bA[4], bB[4];
  stageA(smem[0], 0);
#pragma unroll
  for (int ni = 0; ni < 4; ++ni) bA[ni] = *(const bf16x8*)(Bbase + ni * bstep);
  stageA(smem[1], 32);

#define NT_TILE(KT, BCUR, BNEXT)                                             \
  {                                                                          \
    if ((KT) < NT - 1) asm volatile("s_waitcnt vmcnt(2)" ::: "memory");      \
    else               asm volatile("s_waitcnt vmcnt(0)" ::: "memory");      \
    __builtin_amdgcn_s_barrier();                                            \
    if ((KT) + 1 < NT) {                                                     \
      _Pragma("unroll")                                                      \
      for (int ni = 0; ni < 4; ++ni)                                         \
        BNEXT[ni] = *(const bf16x8*)(Bbase + ni * bstep + ((KT) + 1) * 32);  \
    }                                                                        \
    if ((KT) + 2 < NT) stageA(smem[((KT) + 2) % 3], ((KT) + 2) * 32);        \
    const char* cur = smem[(KT) % 3];                                        \
    bf16x8 aF[4];                                                            \
    _Pragma("unroll")                                                        \
    for (int mi = 0; mi < 4; ++mi) aF[mi] = ldfA(cur, mi);                   \
    _Pragma("unroll")                                                        \
    for (int mi = 0; mi < 4; ++mi)                                           \
      _Pragma("unroll")                                                      \
      for (int ni = 0; ni < 4; ++ni)                                         \
        acc[mi][ni] = __builtin_amdgcn_mfma_f32_16x16x32_bf16(               \
            aF[mi], BCUR[ni], acc[mi][ni], 0, 0, 0);                         \
  }

  for (int kt = 0; kt < NT; kt += 2) {
    NT_TILE(kt, bA, bB);
    NT_TILE(kt + 1, bB, bA);
  }
#undef NT_TILE

#pragma unroll
  for (int mi = 0; mi < 4; ++mi) {
#pragma unroll
    for (int ni = 0; ni < 4; ++ni) {
      const int n = bn + wn + ni * 16 + lrow;
#pragma unroll
      for (int r = 0; r < 4; ++r) {
        const int m = bm + wm + mi * 16 + lgrp * 4 + r;
        const float v = acc[mi][ni][r] * scale;
        if (MODE == 2) {
          ((float*)C)[(size_t)m * N + n] = v;
        } else {
          const int h = m >> 6, d = m & 63;
          const int b = n >> 11, s = n & 2047;
          ((uint16_t*)C)[(((size_t)(b * NHEAD + h) * HDIM + d) * S_LEN) + s] =
              f2bf(v);
        }
      }
    }
  }
}

// ---------------- causal flash attention v4 (unchanged) ----------------
__global__ __launch_bounds__(256, 3) void attn_kernel(
    const uint16_t* __restrict__ Q, const uint16_t* __restrict__ K,
    const uint16_t* __restrict__ Vt, uint16_t* __restrict__ O) {
  __shared__ __align__(16) uint16_t Ks[2][64 * 64];
  __shared__ __align__(16) uint16_t Vs[2][64 * 64];
  __shared__ float Ls[4][32];

  const int t = threadIdx.x, lane = t & 63, w = t >> 6;
  const int qcol = lane & 31, hi = lane >> 5;
  const int id = blockIdx.x;
  const int bh = (id & 7) * 8 + ((id >> 3) & 7);
  const int p = id >> 6;
  const int b = bh >> 5, h = bh & 31;

  const uint16_t* Qbh = Q + (size_t)bh * S_LEN * HDIM;
  const uint16_t* Kbh = K + (size_t)bh * S_LEN * HDIM;
  const uint16_t* Vbh = Vt + (size_t)bh * HDIM * S_LEN;

  const int srow = lane >> 3;
  const int schunk = (lane & 7) ^ srow;

  auto stage = [&](int k0, int bi) {
#pragma unroll
    for (int j = 0; j < 2; ++j) {
      const int r = j * 32 + w * 8 + srow;
      load_lds16(Kbh + (size_t)(k0 + r) * HDIM + schunk * 8,
                 (char*)&Ks[bi][0] + j * 4096 + w * 1024);
      load_lds16(Vbh + (size_t)r * S_LEN + k0 + schunk * 8,
                 (char*)&Vs[bi][0] + j * 4096 + w * 1024);
    }
  };

  for (int pass = 0; pass < 2; ++pass) {
    const int jq = pass ? (15 - p) : p;
    const int qw = jq * 128 + w * 32;
    const int qg = qw + qcol;

    bf16x8 qB[4];
    {
      const uint16_t* qp = Qbh + (size_t)(qw + qcol) * HDIM + hi * 8;
#pragma unroll
      for (int j = 0; j < 4; ++j) qB[j] = *(const bf16x8*)(qp + 16 * j);
    }

    f32x16 oacc0, oacc1;
#pragma unroll
    for (int r = 0; r < 16; ++r) { oacc0[r] = 0.f; oacc1[r] = 0.f; }
    float lsum = 0.f;

    const int nt = 2 * jq + 2;
    for (int kt = 0; kt < nt; ++kt) {
      const int cur = kt & 1;
      const int k0 = kt * 64;
      if (kt == 0) { __syncthreads(); stage(0, 0); }
      __syncthreads();
      if (kt + 1 < nt) stage((kt + 1) * 64, cur ^ 1);

      if (k0 <= qw + 31) {
        const char* Kc = (const char*)&Ks[cur][0];
        const char* Vc = (const char*)&Vs[cur][0];

        f32x16 s0, s1;
#pragma unroll
        for (int r = 0; r < 16; ++r) { s0[r] = 0.f; s1[r] = 0.f; }
        const int rk0 = qcol, rk1 = 32 + qcol;
        const int x0 = rk0 & 7;
        __builtin_amdgcn_s_setprio(1);
#pragma unroll
        for (int j = 0; j < 4; ++j) {
          bf16x8 kf0 = *(const bf16x8*)(Kc + rk0 * 128 + (((2*j+hi) ^ x0) << 4));
          bf16x8 kf1 = *(const bf16x8*)(Kc + rk1 * 128 + (((2*j+hi) ^ x0) << 4));
          s0 = mfma32(kf0, qB[j], s0);
          s1 = mfma32(kf1, qB[j], s1);
        }
        __builtin_amdgcn_s_setprio(0);

        if (k0 + 63 > qw) {
#pragma unroll
          for (int r = 0; r < 16; ++r) {
            const int krow = (r & 3) + 8 * (r >> 2) + 4 * hi;
            s0[r] = (k0 + krow <= qg) ? __expf(s0[r]) : 0.f;
            s1[r] = (k0 + 32 + krow <= qg) ? __expf(s1[r]) : 0.f;
            lsum += s0[r] + s1[r];
          }
        } else {
#pragma unroll
          for (int r = 0; r < 16; ++r) {
            s0[r] = __expf(s0[r]);
            s1[r] = __expf(s1[r]);
            lsum += s0[r] + s1[r];
          }
        }

        bf16x8 paf[4];
#pragma unroll
        for (int tt = 0; tt < 4; ++tt) {
          const int o = 8 * (tt & 1);
          uint32_t a0, a1, a2, a3;
          if (tt < 2) {
            a0 = cvtpk(s0[o + 0], s0[o + 1]);
            a1 = cvtpk(s0[o + 2], s0[o + 3]);
            a2 = cvtpk(s0[o + 4], s0[o + 5]);
            a3 = cvtpk(s0[o + 6], s0[o + 7]);
          } else {
            a0 = cvtpk(s1[o + 0], s1[o + 1]);
            a1 = cvtpk(s1[o + 2], s1[o + 3]);
            a2 = cvtpk(s1[o + 4], s1[o + 5]);
            a3 = cvtpk(s1[o + 6], s1[o + 7]);
          }
          plswap(a0, a2);
          plswap(a1, a3);
          union { uint32_t u[4]; bf16x8 v; } pk;
          pk.u[0] = a0; pk.u[1] = a1; pk.u[2] = a2; pk.u[3] = a3;
          paf[tt] = pk.v;
        }

        __builtin_amdgcn_s_setprio(1);
#pragma unroll
        for (int tt = 0; tt < 4; ++tt) {
          const int c = 2 * tt + hi;
          bf16x8 v0f = *(const bf16x8*)(Vc + rk0 * 128 + ((c ^ x0) << 4));
          bf16x8 v1f = *(const bf16x8*)(Vc + rk1 * 128 + ((c ^ x0) << 4));
          oacc0 = mfma32(paf[tt], v0f, oacc0);
          oacc1 = mfma32(paf[tt], v1f, oacc1);
        }
        __builtin_amdgcn_s_setprio(0);
      }
    }

    lsum += __shfl_xor(lsum, 32, 64);
    if (hi == 0) Ls[w][qcol] = 1.0f / lsum;

#pragma unroll
    for (int r = 0; r < 16; ++r) {
      const int qrow = (r & 3) + 8 * (r >> 2) + 4 * hi;
      const float inv = Ls[w][qrow];
      const size_t base = ((size_t)b * S_LEN + qw + qrow) * 2048 + h * 64;
      O[base + qcol] = f2bf(oacc0[r] * inv);
      O[base + 32 + qcol] = f2bf(oacc1[r] * inv);
    }
  }
}

// ---------------- launcher ----------------
extern "C" void kernel_launch(void* const* d_in, const int* in_sizes, int n_in,
                              void* d_out, int out_size, void* d_ws,
                              size_t ws_size, hipStream_t stream) {
  const float* X  = (const float*)d_in[0];
  const float* Wq = (const float*)d_in[2];
  const float* Wk = (const float*)d_in[3];
  const float* Wv = (const float*)d_in[4];
  const float* Wo = (const float*)d_in[5];
  float* out = (float*)d_out;

  char* ws = (char*)d_ws;
  uint16_t* Xbf = (uint16_t*)ws;                    // 16.78 MB [4096][2048]
  uint16_t* Wqk = (uint16_t*)(ws + 16777216);       // 16.78 MB [4096][2048]
  uint16_t* Qb  = (uint16_t*)(ws + 33554432);       // 16.78 MB [B,NH,S,HD]
  uint16_t* Kb  = (uint16_t*)(ws + 50331648);       // 16.78 MB [B,NH,S,HD]
  uint16_t* Wsm = (uint16_t*)(ws + 67108864);       //  8.39 MB
  uint16_t* Vtb = Wqk;   // Vt aliases Wqk (dead after QK GEMM)
  uint16_t* Ob  = Xbf;   // O aliases Xbf (dead after Vt GEMM)

  const float qscale = 0.125f;  // 1/sqrt(HD)

  conv_batch<<<20480, 256, 0, stream>>>(X, Wq, Wk, Wv, Xbf, Wqk, Wsm);
  gemm_qk<<<512, 256, 0, stream>>>(Xbf, Wqk, Qb, Kb, qscale);
  gemm_nt<1><<<dim3(32, 16), 256, 0, stream>>>(Wsm, Xbf, Vtb, 2048, 4096, 2048, 1.0f);
  attn_kernel<<<dim3(512), 256, 0, stream>>>(Qb, Kb, Vtb, Ob);
  conv_f32_bf16<<<4096, 256, 0, stream>>>(Wo, Wsm, 1048576);
  gemm_nt<2><<<dim3(16, 32), 256, 0, stream>>>(Ob, Wsm, out, 4096, 2048, 2048, 1.0f);
}

// Round 9
// 251.131 us; speedup vs baseline: 1.3034x; 1.3034x over previous
//
#include <hip/hip_runtime.h>
#include <hip/hip_bf16.h>
#include <stdint.h>

// Problem constants: B=2, S=2048, H=2048, NH=32, HD=64
#define S_LEN 2048
#define NHEAD 32
#define HDIM  64

using bf16x8 = __attribute__((ext_vector_type(8))) short;
using f32x4  = __attribute__((ext_vector_type(4))) float;
using f32x16 = __attribute__((ext_vector_type(16))) float;

__device__ __forceinline__ uint16_t f2bf(float f) {
  union { float f; uint32_t u; } c; c.f = f;
  uint32_t u = c.u;
  return (uint16_t)((u + 0x7FFFu + ((u >> 16) & 1u)) >> 16);
}

__device__ __forceinline__ void load_lds16(const void* g, void* l) {
  __builtin_amdgcn_global_load_lds(
      (const __attribute__((address_space(1))) void*)g,
      (__attribute__((address_space(3))) void*)l, 16, 0, 0);
}

__device__ __forceinline__ f32x16 mfma32(bf16x8 a, bf16x8 b, f32x16 c) {
  return __builtin_amdgcn_mfma_f32_32x32x16_bf16(a, b, c, 0, 0, 0);
}

__device__ __forceinline__ uint32_t cvtpk(float lo, float hi_) {
  uint32_t d;
  asm("v_cvt_pk_bf16_f32 %0, %1, %2" : "=v"(d) : "v"(lo), "v"(hi_));
  return d;
}
__device__ __forceinline__ void plswap(uint32_t& a, uint32_t& b) {
  asm volatile("v_permlane32_swap_b32 %0, %1" : "+v"(a), "+v"(b));
}

// ---------------- batched fp32 -> bf16 conversion (X + all 4 weights) -----
__global__ __launch_bounds__(256) void conv_batch(
    const float* __restrict__ X, const float* __restrict__ Wq,
    const float* __restrict__ Wk, const float* __restrict__ Wv,
    const float* __restrict__ Wo, uint16_t* __restrict__ Xbf,
    uint16_t* __restrict__ Wqk, uint16_t* __restrict__ Wvb,
    uint16_t* __restrict__ Wob) {
  int i = blockIdx.x * 256 + threadIdx.x;  // total 6291456
  const float* src; uint16_t* dst; int o;
  if (i < 2097152)      { src = X;  dst = Xbf;           o = i; }
  else if (i < 3145728) { src = Wq; dst = Wqk;           o = i - 2097152; }
  else if (i < 4194304) { src = Wk; dst = Wqk + 4194304; o = i - 3145728; }
  else if (i < 5242880) { src = Wv; dst = Wvb;           o = i - 4194304; }
  else                  { src = Wo; dst = Wob;           o = i - 5242880; }
  float4 v = ((const float4*)src)[o];
  uint64_t packed = (uint64_t)f2bf(v.x) | ((uint64_t)f2bf(v.y) << 16) |
                    ((uint64_t)f2bf(v.z) << 32) | ((uint64_t)f2bf(v.w) << 48);
  ((uint64_t*)dst)[o] = packed;
}

// ---------------- fused QK GEMM: 256x256, BK=32, 3-buf, 2-phase/tile ------
// (r6 version — best measured 72.0 us / MfmaUtil 40)
__global__ __launch_bounds__(512, 2) void gemm_qk(
    const uint16_t* __restrict__ A, const uint16_t* __restrict__ Bw,
    uint16_t* __restrict__ Qo, uint16_t* __restrict__ Ko, float qscale) {
  extern __shared__ char smem[];  // 3 * 32768
  const int t = threadIdx.x;
  const int lane = t & 63, w = t >> 6;
  const int lrow = lane & 15, lgrp = lane >> 4;
  const int wr = w >> 2, wc = w & 3;
  const int id = blockIdx.x;
  const int swz = (id & 7) * 32 + (id >> 3);
  const int bm = (swz & 15) * 256, bn = (swz >> 4) * 256;
  constexpr int NT = 2048 / 32;

  const f32x4 zero4 = {0.f, 0.f, 0.f, 0.f};
  f32x4 acc[8][4];
#pragma unroll
  for (int mi = 0; mi < 8; ++mi)
#pragma unroll
    for (int ni = 0; ni < 4; ++ni) acc[mi][ni] = zero4;

  auto stage_mat = [&](const uint16_t* __restrict__ G, int grow0,
                       char* ldsbase, int kt) {
#pragma unroll
    for (int j = 0; j < 2; ++j) {
      const int s = t + j * 512;
      const int row = s >> 2;
      const int sc = (s & 3) ^ ((row >> 1) & 3);
      load_lds16(G + (size_t)(grow0 + row) * 2048 + kt + sc * 8,
                 ldsbase + j * 8192 + w * 1024);
    }
  };
  auto lda = [&](const char* Ab, int mi) -> bf16x8 {
    const int row = wr * 128 + mi * 16 + lrow;
    return *(const bf16x8*)(Ab + row * 64 + ((lgrp ^ ((row >> 1) & 3)) << 4));
  };
  auto ldb = [&](const char* Bb, int ni) -> bf16x8 {
    const int row = wc * 64 + ni * 16 + lrow;
    return *(const bf16x8*)(Bb + row * 64 + ((lgrp ^ ((row >> 1) & 3)) << 4));
  };

  stage_mat(A, bm, smem, 0);
  stage_mat(Bw, bn, smem + 16384, 0);
  stage_mat(A, bm, smem + 32768, 32);
  stage_mat(Bw, bn, smem + 32768 + 16384, 32);

  for (int kt = 0; kt < NT; ++kt) {
    char* cur = smem + (kt % 3) * 32768;
    char* nx2 = smem + ((kt + 2) % 3) * 32768;
    if (kt < NT - 1) asm volatile("s_waitcnt vmcnt(4)" ::: "memory");
    else             asm volatile("s_waitcnt vmcnt(0)" ::: "memory");
    __builtin_amdgcn_s_barrier();

    bf16x8 aF[4], bF[4];
#pragma unroll
    for (int mi = 0; mi < 4; ++mi) aF[mi] = lda(cur, mi);
#pragma unroll
    for (int ni = 0; ni < 4; ++ni) bF[ni] = ldb(cur + 16384, ni);
    if (kt + 2 < NT) stage_mat(A, bm, nx2, (kt + 2) * 32);
    __builtin_amdgcn_s_barrier();
    asm volatile("s_waitcnt lgkmcnt(0)" ::: "memory");
    __builtin_amdgcn_sched_barrier(0);
    __builtin_amdgcn_s_setprio(1);
#pragma unroll
    for (int mi = 0; mi < 4; ++mi)
#pragma unroll
      for (int ni = 0; ni < 4; ++ni)
        acc[mi][ni] = __builtin_amdgcn_mfma_f32_16x16x32_bf16(
            aF[mi], bF[ni], acc[mi][ni], 0, 0, 0);
    __builtin_amdgcn_s_setprio(0);
    __builtin_amdgcn_s_barrier();

    bf16x8 aG[4];
#pragma unroll
    for (int mi = 0; mi < 4; ++mi) aG[mi] = lda(cur, 4 + mi);
    if (kt + 2 < NT) stage_mat(Bw, bn, nx2 + 16384, (kt + 2) * 32);
    __builtin_amdgcn_s_barrier();
    asm volatile("s_waitcnt lgkmcnt(0)" ::: "memory");
    __builtin_amdgcn_sched_barrier(0);
    __builtin_amdgcn_s_setprio(1);
#pragma unroll
    for (int mi = 0; mi < 4; ++mi)
#pragma unroll
      for (int ni = 0; ni < 4; ++ni)
        acc[4 + mi][ni] = __builtin_amdgcn_mfma_f32_16x16x32_bf16(
            aG[mi], bF[ni], acc[4 + mi][ni], 0, 0, 0);
    __builtin_amdgcn_s_setprio(0);
  }

  const bool isQ = (bn < 2048);
#pragma unroll
  for (int mi = 0; mi < 8; ++mi) {
#pragma unroll
    for (int ni = 0; ni < 4; ++ni) {
      const int n = bn + wc * 64 + ni * 16 + lrow;
      const int n2 = isQ ? n : (n - 2048);
      const int h = n2 >> 6, d = n2 & 63;
#pragma unroll
      for (int r = 0; r < 4; ++r) {
        const int m = bm + wr * 128 + mi * 16 + lgrp * 4 + r;
        const int b = m >> 11, s = m & 2047;
        const size_t off = (((size_t)(b * NHEAD + h) * S_LEN + s) * HDIM) + d;
        if (isQ) Qo[off] = f2bf(acc[mi][ni][r] * qscale);
        else     Ko[off] = f2bf(acc[mi][ni][r]);
      }
    }
  }
}

// ---------------- NT GEMM 128^2, BK=32, 3-buf, 1 barrier/tile (r6) --------
template<int MODE>
__global__ __launch_bounds__(256, 3) void gemm_nt(
    const uint16_t* __restrict__ A, const uint16_t* __restrict__ B,
    void* __restrict__ C, int M, int N, int K, float scale) {
  __shared__ __align__(16) char smem[3][16384];

  const int t = threadIdx.x;
  const int lane = t & 63, w = t >> 6;
  const int lrow = lane & 15, lgrp = lane >> 4;
  const int bm = blockIdx.y * 128, bn = blockIdx.x * 128;
  const int wm = (w >> 1) * 64, wn = (w & 1) * 64;
  const int NT = K / 32;

  const f32x4 zero4 = {0.f, 0.f, 0.f, 0.f};
  f32x4 acc[4][4];
#pragma unroll
  for (int mi = 0; mi < 4; ++mi)
#pragma unroll
    for (int ni = 0; ni < 4; ++ni) acc[mi][ni] = zero4;

  auto stage_mat = [&](const uint16_t* __restrict__ G, int grow0,
                       char* ldsbase, int kt) {
#pragma unroll
    for (int j = 0; j < 2; ++j) {
      const int s = t + j * 256;
      const int row = s >> 2;
      const int sc = (s & 3) ^ ((row >> 1) & 3);
      load_lds16(G + (size_t)(grow0 + row) * K + kt + sc * 8,
                 ldsbase + j * 4096 + w * 1024);
    }
  };
  auto ldf = [&](const char* Mb, int base, int i) -> bf16x8 {
    const int row = base + i * 16 + lrow;
    return *(const bf16x8*)(Mb + row * 64 + ((lgrp ^ ((row >> 1) & 3)) << 4));
  };

  stage_mat(A, bm, smem[0], 0);
  stage_mat(B, bn, smem[0] + 8192, 0);
  stage_mat(A, bm, smem[1], 32);
  stage_mat(B, bn, smem[1] + 8192, 32);

  for (int kt = 0; kt < NT; ++kt) {
    char* cur = smem[kt % 3];
    if (kt < NT - 1) asm volatile("s_waitcnt vmcnt(4)" ::: "memory");
    else             asm volatile("s_waitcnt vmcnt(0)" ::: "memory");
    __builtin_amdgcn_s_barrier();

    if (kt + 2 < NT) {
      char* nx2 = smem[(kt + 2) % 3];
      stage_mat(A, bm, nx2, (kt + 2) * 32);
      stage_mat(B, bn, nx2 + 8192, (kt + 2) * 32);
    }

    bf16x8 aF[4], bF[4];
#pragma unroll
    for (int mi = 0; mi < 4; ++mi) aF[mi] = ldf(cur, wm, mi);
#pragma unroll
    for (int ni = 0; ni < 4; ++ni) bF[ni] = ldf(cur + 8192, wn, ni);
#pragma unroll
    for (int mi = 0; mi < 4; ++mi)
#pragma unroll
      for (int ni = 0; ni < 4; ++ni)
        acc[mi][ni] = __builtin_amdgcn_mfma_f32_16x16x32_bf16(
            aF[mi], bF[ni], acc[mi][ni], 0, 0, 0);
  }

#pragma unroll
  for (int mi = 0; mi < 4; ++mi) {
#pragma unroll
    for (int ni = 0; ni < 4; ++ni) {
      const int n = bn + wn + ni * 16 + lrow;
#pragma unroll
      for (int r = 0; r < 4; ++r) {
        const int m = bm + wm + mi * 16 + lgrp * 4 + r;
        const float v = acc[mi][ni][r] * scale;
        if (MODE == 2) {
          ((float*)C)[(size_t)m * N + n] = v;
        } else {
          const int h = m >> 6, d = m & 63;
          const int b = n >> 11, s = n & 2047;
          ((uint16_t*)C)[(((size_t)(b * NHEAD + h) * HDIM + d) * S_LEN) + s] =
              f2bf(v);
        }
      }
    }
  }
}

// ---------------- causal flash attention v5: merged paired q-tiles --------
// One KV sweep per block: loop1 computes q-tiles A=p and B=15-p together
// against shared staged K/V (PV shares V-fragment reads); A's output is
// written when its causal range ends; loop2 finishes B alone. Staged tiles
// per block drop from 36 to 34-2p; single pipeline, no inter-pass drain.
__global__ __launch_bounds__(256) void attn_kernel(
    const uint16_t* __restrict__ Q, const uint16_t* __restrict__ K,
    const uint16_t* __restrict__ Vt, uint16_t* __restrict__ O) {
  __shared__ __align__(16) uint16_t Ks[2][64 * 64];
  __shared__ __align__(16) uint16_t Vs[2][64 * 64];
  __shared__ float Ls[4][32];

  const int t = threadIdx.x, lane = t & 63, w = t >> 6;
  const int qcol = lane & 31, hi = lane >> 5;
  const int id = blockIdx.x;
  const int bh = (id & 7) * 8 + ((id >> 3) & 7);  // 8 heads per XCD
  const int p = id >> 6;                           // 0..7
  const int b = bh >> 5, h = bh & 31;

  const uint16_t* Qbh = Q + (size_t)bh * S_LEN * HDIM;
  const uint16_t* Kbh = K + (size_t)bh * S_LEN * HDIM;
  const uint16_t* Vbh = Vt + (size_t)bh * HDIM * S_LEN;

  const int srow = lane >> 3;
  const int schunk = (lane & 7) ^ srow;

  auto stage = [&](int k0, int bi) {
#pragma unroll
    for (int j = 0; j < 2; ++j) {
      const int r = j * 32 + w * 8 + srow;
      load_lds16(Kbh + (size_t)(k0 + r) * HDIM + schunk * 8,
                 (char*)&Ks[bi][0] + j * 4096 + w * 1024);
      load_lds16(Vbh + (size_t)r * S_LEN + k0 + schunk * 8,
                 (char*)&Vs[bi][0] + j * 4096 + w * 1024);
    }
  };

  const int qtA = p, qtB = 15 - p;
  const int qwA = qtA * 128 + w * 32, qwB = qtB * 128 + w * 32;
  const int qgA = qwA + qcol, qgB = qwB + qcol;
  const int ntA = 2 * qtA + 2, ntB = 2 * qtB + 2;  // ntB >= 18 > ntA

  bf16x8 qA[4], qB[4];
  {
    const uint16_t* qp = Qbh + (size_t)qgA * HDIM + hi * 8;
#pragma unroll
    for (int j = 0; j < 4; ++j) qA[j] = *(const bf16x8*)(qp + 16 * j);
    const uint16_t* qp2 = Qbh + (size_t)qgB * HDIM + hi * 8;
#pragma unroll
    for (int j = 0; j < 4; ++j) qB[j] = *(const bf16x8*)(qp2 + 16 * j);
  }

  f32x16 oA0, oA1, oB0, oB1;
#pragma unroll
  for (int r = 0; r < 16; ++r) { oA0[r] = 0.f; oA1[r] = 0.f;
                                 oB0[r] = 0.f; oB1[r] = 0.f; }
  float lsA = 0.f, lsB = 0.f;

  const int rk0 = qcol, rk1 = 32 + qcol;
  const int x0 = qcol & 7;

  // QK^T (swapped) + no-max softmax + P->A-frag repack for one state
  auto qk_paf = [&](const bf16x8 (&qf)[4], int qwl, int qgl, int k0,
                    const char* Kc, bf16x8 (&paf)[4], float& lsum) {
    f32x16 s0, s1;
#pragma unroll
    for (int r = 0; r < 16; ++r) { s0[r] = 0.f; s1[r] = 0.f; }
    __builtin_amdgcn_s_setprio(1);
#pragma unroll
    for (int j = 0; j < 4; ++j) {
      bf16x8 kf0 = *(const bf16x8*)(Kc + rk0 * 128 + (((2*j+hi) ^ x0) << 4));
      bf16x8 kf1 = *(const bf16x8*)(Kc + rk1 * 128 + (((2*j+hi) ^ x0) << 4));
      s0 = mfma32(kf0, qf[j], s0);
      s1 = mfma32(kf1, qf[j], s1);
    }
    __builtin_amdgcn_s_setprio(0);
    if (k0 + 63 > qwl) {
#pragma unroll
      for (int r = 0; r < 16; ++r) {
        const int krow = (r & 3) + 8 * (r >> 2) + 4 * hi;
        s0[r] = (k0 + krow <= qgl) ? __expf(s0[r]) : 0.f;
        s1[r] = (k0 + 32 + krow <= qgl) ? __expf(s1[r]) : 0.f;
        lsum += s0[r] + s1[r];
      }
    } else {
#pragma unroll
      for (int r = 0; r < 16; ++r) {
        s0[r] = __expf(s0[r]);
        s1[r] = __expf(s1[r]);
        lsum += s0[r] + s1[r];
      }
    }
#pragma unroll
    for (int tt = 0; tt < 4; ++tt) {
      const int o = 8 * (tt & 1);
      uint32_t a0, a1, a2, a3;
      if (tt < 2) {
        a0 = cvtpk(s0[o + 0], s0[o + 1]);
        a1 = cvtpk(s0[o + 2], s0[o + 3]);
        a2 = cvtpk(s0[o + 4], s0[o + 5]);
        a3 = cvtpk(s0[o + 6], s0[o + 7]);
      } else {
        a0 = cvtpk(s1[o + 0], s1[o + 1]);
        a1 = cvtpk(s1[o + 2], s1[o + 3]);
        a2 = cvtpk(s1[o + 4], s1[o + 5]);
        a3 = cvtpk(s1[o + 6], s1[o + 7]);
      }
      plswap(a0, a2);
      plswap(a1, a3);
      union { uint32_t u[4]; bf16x8 v; } pk;
      pk.u[0] = a0; pk.u[1] = a1; pk.u[2] = a2; pk.u[3] = a3;
      paf[tt] = pk.v;
    }
  };

  auto write_out = [&](const f32x16& o0, const f32x16& o1, int qwl,
                       float lsum) {
    lsum += __shfl_xor(lsum, 32, 64);
    if (hi == 0) Ls[w][qcol] = 1.0f / lsum;
#pragma unroll
    for (int r = 0; r < 16; ++r) {
      const int qrow = (r & 3) + 8 * (r >> 2) + 4 * hi;
      const float inv = Ls[w][qrow];
      const size_t base = ((size_t)b * S_LEN + qwl + qrow) * 2048 + h * 64;
      O[base + qcol] = f2bf(o0[r] * inv);
      O[base + 32 + qcol] = f2bf(o1[r] * inv);
    }
  };

  stage(0, 0);

  // ---- loop1: both states, shared staging + shared V reads ----
  for (int kt = 0; kt < ntA; ++kt) {
    const int cur = kt & 1;
    const int k0 = kt * 64;
    __syncthreads();                       // stage(kt) landed
    if (kt + 1 < ntB) stage((kt + 1) * 64, cur ^ 1);

    const char* Kc = (const char*)&Ks[cur][0];
    const char* Vc = (const char*)&Vs[cur][0];
    const bool actA = (k0 <= qwA + 31);

    bf16x8 pafA[4], pafB[4];
    if (actA) qk_paf(qA, qwA, qgA, k0, Kc, pafA, lsA);
    qk_paf(qB, qwB, qgB, k0, Kc, pafB, lsB);

    __builtin_amdgcn_s_setprio(1);
#pragma unroll
    for (int tt = 0; tt < 4; ++tt) {
      const int c = 2 * tt + hi;
      bf16x8 v0f = *(const bf16x8*)(Vc + rk0 * 128 + ((c ^ x0) << 4));
      bf16x8 v1f = *(const bf16x8*)(Vc + rk1 * 128 + ((c ^ x0) << 4));
      if (actA) {
        oA0 = mfma32(pafA[tt], v0f, oA0);
        oA1 = mfma32(pafA[tt], v1f, oA1);
      }
      oB0 = mfma32(pafB[tt], v0f, oB0);
      oB1 = mfma32(pafB[tt], v1f, oB1);
    }
    __builtin_amdgcn_s_setprio(0);
  }

  write_out(oA0, oA1, qwA, lsA);  // A complete

  // ---- loop2: B only ----
  for (int kt = ntA; kt < ntB; ++kt) {
    const int cur = kt & 1;
    const int k0 = kt * 64;
    __syncthreads();
    if (kt + 1 < ntB) stage((kt + 1) * 64, cur ^ 1);

    const char* Kc = (const char*)&Ks[cur][0];
    const char* Vc = (const char*)&Vs[cur][0];
    if (k0 > qwB + 31) continue;  // wave past its causal range (tail tiles)

    bf16x8 pafB[4];
    qk_paf(qB, qwB, qgB, k0, Kc, pafB, lsB);

    __builtin_amdgcn_s_setprio(1);
#pragma unroll
    for (int tt = 0; tt < 4; ++tt) {
      const int c = 2 * tt + hi;
      bf16x8 v0f = *(const bf16x8*)(Vc + rk0 * 128 + ((c ^ x0) << 4));
      bf16x8 v1f = *(const bf16x8*)(Vc + rk1 * 128 + ((c ^ x0) << 4));
      oB0 = mfma32(pafB[tt], v0f, oB0);
      oB1 = mfma32(pafB[tt], v1f, oB1);
    }
    __builtin_amdgcn_s_setprio(0);
  }

  write_out(oB0, oB1, qwB, lsB);
}

// ---------------- launcher ----------------
extern "C" void kernel_launch(void* const* d_in, const int* in_sizes, int n_in,
                              void* d_out, int out_size, void* d_ws,
                              size_t ws_size, hipStream_t stream) {
  const float* X  = (const float*)d_in[0];
  const float* Wq = (const float*)d_in[2];
  const float* Wk = (const float*)d_in[3];
  const float* Wv = (const float*)d_in[4];
  const float* Wo = (const float*)d_in[5];
  float* out = (float*)d_out;

  char* ws = (char*)d_ws;
  uint16_t* Xbf = (uint16_t*)ws;                    // 16.78 MB [4096][2048]
  uint16_t* Wqk = (uint16_t*)(ws + 16777216);       // 16.78 MB [4096][2048]
  uint16_t* Qb  = (uint16_t*)(ws + 33554432);       // 16.78 MB [B,NH,S,HD]
  uint16_t* Kb  = (uint16_t*)(ws + 50331648);       // 16.78 MB [B,NH,S,HD]
  uint16_t* Wsm = (uint16_t*)(ws + 67108864);       //  8.39 MB (Wv bf16)
  uint16_t* Wob = (uint16_t*)(ws + 75497472);       //  8.39 MB (Wo bf16)
  uint16_t* Vtb = Wqk;   // Vt aliases Wqk (dead after QK GEMM)
  uint16_t* Ob  = Xbf;   // O aliases Xbf (dead after Vt GEMM)

  const float qscale = 0.125f;  // 1/sqrt(HD)

  hipFuncSetAttribute((const void*)gemm_qk,
                      hipFuncAttributeMaxDynamicSharedMemorySize, 98304);

  conv_batch<<<24576, 256, 0, stream>>>(X, Wq, Wk, Wv, Wo, Xbf, Wqk, Wsm, Wob);
  gemm_qk<<<256, 512, 98304, stream>>>(Xbf, Wqk, Qb, Kb, qscale);
  gemm_nt<1><<<dim3(32, 16), 256, 0, stream>>>(Wsm, Xbf, Vtb, 2048, 4096, 2048, 1.0f);
  attn_kernel<<<dim3(512), 256, 0, stream>>>(Qb, Kb, Vtb, Ob);
  gemm_nt<2><<<dim3(16, 32), 256, 0, stream>>>(Ob, Wob, out, 4096, 2048, 2048, 1.0f);
}

// Round 10
// 229.126 us; speedup vs baseline: 1.4286x; 1.0960x over previous
//
#include <hip/hip_runtime.h>
#include <hip/hip_bf16.h>
#include <stdint.h>

// Problem constants: B=2, S=2048, H=2048, NH=32, HD=64
#define S_LEN 2048
#define NHEAD 32
#define HDIM  64

using bf16x8 = __attribute__((ext_vector_type(8))) short;
using f32x4  = __attribute__((ext_vector_type(4))) float;
using f32x16 = __attribute__((ext_vector_type(16))) float;

__device__ __forceinline__ uint16_t f2bf(float f) {
  union { float f; uint32_t u; } c; c.f = f;
  uint32_t u = c.u;
  return (uint16_t)((u + 0x7FFFu + ((u >> 16) & 1u)) >> 16);
}

__device__ __forceinline__ void load_lds16(const void* g, void* l) {
  __builtin_amdgcn_global_load_lds(
      (const __attribute__((address_space(1))) void*)g,
      (__attribute__((address_space(3))) void*)l, 16, 0, 0);
}

__device__ __forceinline__ f32x16 mfma32(bf16x8 a, bf16x8 b, f32x16 c) {
  return __builtin_amdgcn_mfma_f32_32x32x16_bf16(a, b, c, 0, 0, 0);
}

__device__ __forceinline__ uint32_t cvtpk(float lo, float hi_) {
  uint32_t d;
  asm("v_cvt_pk_bf16_f32 %0, %1, %2" : "=v"(d) : "v"(lo), "v"(hi_));
  return d;
}
__device__ __forceinline__ void plswap(uint32_t& a, uint32_t& b) {
  asm volatile("v_permlane32_swap_b32 %0, %1" : "+v"(a), "+v"(b));
}

// ---------------- batched fp32 -> bf16 conversion (X + all 4 weights) -----
__global__ __launch_bounds__(256) void conv_batch(
    const float* __restrict__ X, const float* __restrict__ Wq,
    const float* __restrict__ Wk, const float* __restrict__ Wv,
    const float* __restrict__ Wo, uint16_t* __restrict__ Xbf,
    uint16_t* __restrict__ Wqk, uint16_t* __restrict__ Wvb,
    uint16_t* __restrict__ Wob) {
  int i = blockIdx.x * 256 + threadIdx.x;  // total 6291456
  const float* src; uint16_t* dst; int o;
  if (i < 2097152)      { src = X;  dst = Xbf;           o = i; }
  else if (i < 3145728) { src = Wq; dst = Wqk;           o = i - 2097152; }
  else if (i < 4194304) { src = Wk; dst = Wqk + 4194304; o = i - 3145728; }
  else if (i < 5242880) { src = Wv; dst = Wvb;           o = i - 4194304; }
  else                  { src = Wo; dst = Wob;           o = i - 5242880; }
  float4 v = ((const float4*)src)[o];
  uint64_t packed = (uint64_t)f2bf(v.x) | ((uint64_t)f2bf(v.y) << 16) |
                    ((uint64_t)f2bf(v.z) << 32) | ((uint64_t)f2bf(v.w) << 48);
  ((uint64_t*)dst)[o] = packed;
}

// ---------------- fused QK GEMM: 256x256, BK=32, 3-buf, 2-phase/tile ------
// (r6 — best measured 72.0 us / MfmaUtil 40; family plateau ~950 TF)
__global__ __launch_bounds__(512, 2) void gemm_qk(
    const uint16_t* __restrict__ A, const uint16_t* __restrict__ Bw,
    uint16_t* __restrict__ Qo, uint16_t* __restrict__ Ko, float qscale) {
  extern __shared__ char smem[];  // 3 * 32768
  const int t = threadIdx.x;
  const int lane = t & 63, w = t >> 6;
  const int lrow = lane & 15, lgrp = lane >> 4;
  const int wr = w >> 2, wc = w & 3;
  const int id = blockIdx.x;
  const int swz = (id & 7) * 32 + (id >> 3);
  const int bm = (swz & 15) * 256, bn = (swz >> 4) * 256;
  constexpr int NT = 2048 / 32;

  const f32x4 zero4 = {0.f, 0.f, 0.f, 0.f};
  f32x4 acc[8][4];
#pragma unroll
  for (int mi = 0; mi < 8; ++mi)
#pragma unroll
    for (int ni = 0; ni < 4; ++ni) acc[mi][ni] = zero4;

  auto stage_mat = [&](const uint16_t* __restrict__ G, int grow0,
                       char* ldsbase, int kt) {
#pragma unroll
    for (int j = 0; j < 2; ++j) {
      const int s = t + j * 512;
      const int row = s >> 2;
      const int sc = (s & 3) ^ ((row >> 1) & 3);
      load_lds16(G + (size_t)(grow0 + row) * 2048 + kt + sc * 8,
                 ldsbase + j * 8192 + w * 1024);
    }
  };
  auto lda = [&](const char* Ab, int mi) -> bf16x8 {
    const int row = wr * 128 + mi * 16 + lrow;
    return *(const bf16x8*)(Ab + row * 64 + ((lgrp ^ ((row >> 1) & 3)) << 4));
  };
  auto ldb = [&](const char* Bb, int ni) -> bf16x8 {
    const int row = wc * 64 + ni * 16 + lrow;
    return *(const bf16x8*)(Bb + row * 64 + ((lgrp ^ ((row >> 1) & 3)) << 4));
  };

  stage_mat(A, bm, smem, 0);
  stage_mat(Bw, bn, smem + 16384, 0);
  stage_mat(A, bm, smem + 32768, 32);
  stage_mat(Bw, bn, smem + 32768 + 16384, 32);

  for (int kt = 0; kt < NT; ++kt) {
    char* cur = smem + (kt % 3) * 32768;
    char* nx2 = smem + ((kt + 2) % 3) * 32768;
    if (kt < NT - 1) asm volatile("s_waitcnt vmcnt(4)" ::: "memory");
    else             asm volatile("s_waitcnt vmcnt(0)" ::: "memory");
    __builtin_amdgcn_s_barrier();

    bf16x8 aF[4], bF[4];
#pragma unroll
    for (int mi = 0; mi < 4; ++mi) aF[mi] = lda(cur, mi);
#pragma unroll
    for (int ni = 0; ni < 4; ++ni) bF[ni] = ldb(cur + 16384, ni);
    if (kt + 2 < NT) stage_mat(A, bm, nx2, (kt + 2) * 32);
    __builtin_amdgcn_s_barrier();
    asm volatile("s_waitcnt lgkmcnt(0)" ::: "memory");
    __builtin_amdgcn_sched_barrier(0);
    __builtin_amdgcn_s_setprio(1);
#pragma unroll
    for (int mi = 0; mi < 4; ++mi)
#pragma unroll
      for (int ni = 0; ni < 4; ++ni)
        acc[mi][ni] = __builtin_amdgcn_mfma_f32_16x16x32_bf16(
            aF[mi], bF[ni], acc[mi][ni], 0, 0, 0);
    __builtin_amdgcn_s_setprio(0);
    __builtin_amdgcn_s_barrier();

    bf16x8 aG[4];
#pragma unroll
    for (int mi = 0; mi < 4; ++mi) aG[mi] = lda(cur, 4 + mi);
    if (kt + 2 < NT) stage_mat(Bw, bn, nx2 + 16384, (kt + 2) * 32);
    __builtin_amdgcn_s_barrier();
    asm volatile("s_waitcnt lgkmcnt(0)" ::: "memory");
    __builtin_amdgcn_sched_barrier(0);
    __builtin_amdgcn_s_setprio(1);
#pragma unroll
    for (int mi = 0; mi < 4; ++mi)
#pragma unroll
      for (int ni = 0; ni < 4; ++ni)
        acc[4 + mi][ni] = __builtin_amdgcn_mfma_f32_16x16x32_bf16(
            aG[mi], bF[ni], acc[4 + mi][ni], 0, 0, 0);
    __builtin_amdgcn_s_setprio(0);
  }

  const bool isQ = (bn < 2048);
#pragma unroll
  for (int mi = 0; mi < 8; ++mi) {
#pragma unroll
    for (int ni = 0; ni < 4; ++ni) {
      const int n = bn + wc * 64 + ni * 16 + lrow;
      const int n2 = isQ ? n : (n - 2048);
      const int h = n2 >> 6, d = n2 & 63;
#pragma unroll
      for (int r = 0; r < 4; ++r) {
        const int m = bm + wr * 128 + mi * 16 + lgrp * 4 + r;
        const int b = m >> 11, s = m & 2047;
        const size_t off = (((size_t)(b * NHEAD + h) * S_LEN + s) * HDIM) + d;
        if (isQ) Qo[off] = f2bf(acc[mi][ni][r] * qscale);
        else     Ko[off] = f2bf(acc[mi][ni][r]);
      }
    }
  }
}

// ---------------- NT GEMM 128^2, BK=32, 3-buf, 1 barrier/tile (r6) --------
template<int MODE>
__global__ __launch_bounds__(256, 3) void gemm_nt(
    const uint16_t* __restrict__ A, const uint16_t* __restrict__ B,
    void* __restrict__ C, int M, int N, int K, float scale) {
  __shared__ __align__(16) char smem[3][16384];

  const int t = threadIdx.x;
  const int lane = t & 63, w = t >> 6;
  const int lrow = lane & 15, lgrp = lane >> 4;
  const int bm = blockIdx.y * 128, bn = blockIdx.x * 128;
  const int wm = (w >> 1) * 64, wn = (w & 1) * 64;
  const int NT = K / 32;

  const f32x4 zero4 = {0.f, 0.f, 0.f, 0.f};
  f32x4 acc[4][4];
#pragma unroll
  for (int mi = 0; mi < 4; ++mi)
#pragma unroll
    for (int ni = 0; ni < 4; ++ni) acc[mi][ni] = zero4;

  auto stage_mat = [&](const uint16_t* __restrict__ G, int grow0,
                       char* ldsbase, int kt) {
#pragma unroll
    for (int j = 0; j < 2; ++j) {
      const int s = t + j * 256;
      const int row = s >> 2;
      const int sc = (s & 3) ^ ((row >> 1) & 3);
      load_lds16(G + (size_t)(grow0 + row) * K + kt + sc * 8,
                 ldsbase + j * 4096 + w * 1024);
    }
  };
  auto ldf = [&](const char* Mb, int base, int i) -> bf16x8 {
    const int row = base + i * 16 + lrow;
    return *(const bf16x8*)(Mb + row * 64 + ((lgrp ^ ((row >> 1) & 3)) << 4));
  };

  stage_mat(A, bm, smem[0], 0);
  stage_mat(B, bn, smem[0] + 8192, 0);
  stage_mat(A, bm, smem[1], 32);
  stage_mat(B, bn, smem[1] + 8192, 32);

  for (int kt = 0; kt < NT; ++kt) {
    char* cur = smem[kt % 3];
    if (kt < NT - 1) asm volatile("s_waitcnt vmcnt(4)" ::: "memory");
    else             asm volatile("s_waitcnt vmcnt(0)" ::: "memory");
    __builtin_amdgcn_s_barrier();

    if (kt + 2 < NT) {
      char* nx2 = smem[(kt + 2) % 3];
      stage_mat(A, bm, nx2, (kt + 2) * 32);
      stage_mat(B, bn, nx2 + 8192, (kt + 2) * 32);
    }

    bf16x8 aF[4], bF[4];
#pragma unroll
    for (int mi = 0; mi < 4; ++mi) aF[mi] = ldf(cur, wm, mi);
#pragma unroll
    for (int ni = 0; ni < 4; ++ni) bF[ni] = ldf(cur + 8192, wn, ni);
#pragma unroll
    for (int mi = 0; mi < 4; ++mi)
#pragma unroll
      for (int ni = 0; ni < 4; ++ni)
        acc[mi][ni] = __builtin_amdgcn_mfma_f32_16x16x32_bf16(
            aF[mi], bF[ni], acc[mi][ni], 0, 0, 0);
  }

#pragma unroll
  for (int mi = 0; mi < 4; ++mi) {
#pragma unroll
    for (int ni = 0; ni < 4; ++ni) {
      const int n = bn + wn + ni * 16 + lrow;
#pragma unroll
      for (int r = 0; r < 4; ++r) {
        const int m = bm + wm + mi * 16 + lgrp * 4 + r;
        const float v = acc[mi][ni][r] * scale;
        if (MODE == 2) {
          ((float*)C)[(size_t)m * N + n] = v;
        } else {
          const int h = m >> 6, d = m & 63;
          const int b = n >> 11, s = n & 2047;
          ((uint16_t*)C)[(((size_t)(b * NHEAD + h) * HDIM + d) * S_LEN) + s] =
              f2bf(v);
        }
      }
    }
  }
}

// ---------------- causal flash attention v4 (r4 exact — proven best) ------
// 4 waves x 32 q-rows, KVBLK=64 double-buffered, swapped QK, in-reg P via
// cvt_pk + permlane32_swap, paired q-tiles (p, 15-p): uniform 36 tiles/block.
__global__ __launch_bounds__(256, 3) void attn_kernel(
    const uint16_t* __restrict__ Q, const uint16_t* __restrict__ K,
    const uint16_t* __restrict__ Vt, uint16_t* __restrict__ O) {
  __shared__ __align__(16) uint16_t Ks[2][64 * 64];
  __shared__ __align__(16) uint16_t Vs[2][64 * 64];
  __shared__ float Ls[4][32];

  const int t = threadIdx.x, lane = t & 63, w = t >> 6;
  const int qcol = lane & 31, hi = lane >> 5;
  const int id = blockIdx.x;
  const int bh = (id & 7) * 8 + ((id >> 3) & 7);  // 8 heads per XCD
  const int p = id >> 6;                           // 0..7
  const int b = bh >> 5, h = bh & 31;

  const uint16_t* Qbh = Q + (size_t)bh * S_LEN * HDIM;
  const uint16_t* Kbh = K + (size_t)bh * S_LEN * HDIM;
  const uint16_t* Vbh = Vt + (size_t)bh * HDIM * S_LEN;

  const int srow = lane >> 3;
  const int schunk = (lane & 7) ^ srow;

  auto stage = [&](int k0, int bi) {
#pragma unroll
    for (int j = 0; j < 2; ++j) {
      const int r = j * 32 + w * 8 + srow;
      load_lds16(Kbh + (size_t)(k0 + r) * HDIM + schunk * 8,
                 (char*)&Ks[bi][0] + j * 4096 + w * 1024);
      load_lds16(Vbh + (size_t)r * S_LEN + k0 + schunk * 8,
                 (char*)&Vs[bi][0] + j * 4096 + w * 1024);
    }
  };

  for (int pass = 0; pass < 2; ++pass) {
    const int jq = pass ? (15 - p) : p;
    const int qw = jq * 128 + w * 32;
    const int qg = qw + qcol;

    bf16x8 qB[4];
    {
      const uint16_t* qp = Qbh + (size_t)(qw + qcol) * HDIM + hi * 8;
#pragma unroll
      for (int j = 0; j < 4; ++j) qB[j] = *(const bf16x8*)(qp + 16 * j);
    }

    f32x16 oacc0, oacc1;
#pragma unroll
    for (int r = 0; r < 16; ++r) { oacc0[r] = 0.f; oacc1[r] = 0.f; }
    float lsum = 0.f;

    const int nt = 2 * jq + 2;
    for (int kt = 0; kt < nt; ++kt) {
      const int cur = kt & 1;
      const int k0 = kt * 64;
      if (kt == 0) { __syncthreads(); stage(0, 0); }
      __syncthreads();
      if (kt + 1 < nt) stage((kt + 1) * 64, cur ^ 1);

      if (k0 <= qw + 31) {
        const char* Kc = (const char*)&Ks[cur][0];
        const char* Vc = (const char*)&Vs[cur][0];

        f32x16 s0, s1;
#pragma unroll
        for (int r = 0; r < 16; ++r) { s0[r] = 0.f; s1[r] = 0.f; }
        const int rk0 = qcol, rk1 = 32 + qcol;
        const int x0 = rk0 & 7;
        __builtin_amdgcn_s_setprio(1);
#pragma unroll
        for (int j = 0; j < 4; ++j) {
          bf16x8 kf0 = *(const bf16x8*)(Kc + rk0 * 128 + (((2*j+hi) ^ x0) << 4));
          bf16x8 kf1 = *(const bf16x8*)(Kc + rk1 * 128 + (((2*j+hi) ^ x0) << 4));
          s0 = mfma32(kf0, qB[j], s0);
          s1 = mfma32(kf1, qB[j], s1);
        }
        __builtin_amdgcn_s_setprio(0);

        if (k0 + 63 > qw) {
#pragma unroll
          for (int r = 0; r < 16; ++r) {
            const int krow = (r & 3) + 8 * (r >> 2) + 4 * hi;
            s0[r] = (k0 + krow <= qg) ? __expf(s0[r]) : 0.f;
            s1[r] = (k0 + 32 + krow <= qg) ? __expf(s1[r]) : 0.f;
            lsum += s0[r] + s1[r];
          }
        } else {
#pragma unroll
          for (int r = 0; r < 16; ++r) {
            s0[r] = __expf(s0[r]);
            s1[r] = __expf(s1[r]);
            lsum += s0[r] + s1[r];
          }
        }

        bf16x8 paf[4];
#pragma unroll
        for (int tt = 0; tt < 4; ++tt) {
          const int o = 8 * (tt & 1);
          uint32_t a0, a1, a2, a3;
          if (tt < 2) {
            a0 = cvtpk(s0[o + 0], s0[o + 1]);
            a1 = cvtpk(s0[o + 2], s0[o + 3]);
            a2 = cvtpk(s0[o + 4], s0[o + 5]);
            a3 = cvtpk(s0[o + 6], s0[o + 7]);
          } else {
            a0 = cvtpk(s1[o + 0], s1[o + 1]);
            a1 = cvtpk(s1[o + 2], s1[o + 3]);
            a2 = cvtpk(s1[o + 4], s1[o + 5]);
            a3 = cvtpk(s1[o + 6], s1[o + 7]);
          }
          plswap(a0, a2);
          plswap(a1, a3);
          union { uint32_t u[4]; bf16x8 v; } pk;
          pk.u[0] = a0; pk.u[1] = a1; pk.u[2] = a2; pk.u[3] = a3;
          paf[tt] = pk.v;
        }

        __builtin_amdgcn_s_setprio(1);
#pragma unroll
        for (int tt = 0; tt < 4; ++tt) {
          const int c = 2 * tt + hi;
          bf16x8 v0f = *(const bf16x8*)(Vc + rk0 * 128 + ((c ^ x0) << 4));
          bf16x8 v1f = *(const bf16x8*)(Vc + rk1 * 128 + ((c ^ x0) << 4));
          oacc0 = mfma32(paf[tt], v0f, oacc0);
          oacc1 = mfma32(paf[tt], v1f, oacc1);
        }
        __builtin_amdgcn_s_setprio(0);
      }
    }

    lsum += __shfl_xor(lsum, 32, 64);
    if (hi == 0) Ls[w][qcol] = 1.0f / lsum;

#pragma unroll
    for (int r = 0; r < 16; ++r) {
      const int qrow = (r & 3) + 8 * (r >> 2) + 4 * hi;
      const float inv = Ls[w][qrow];
      const size_t base = ((size_t)b * S_LEN + qw + qrow) * 2048 + h * 64;
      O[base + qcol] = f2bf(oacc0[r] * inv);
      O[base + 32 + qcol] = f2bf(oacc1[r] * inv);
    }
  }
}

// ---------------- launcher ----------------
extern "C" void kernel_launch(void* const* d_in, const int* in_sizes, int n_in,
                              void* d_out, int out_size, void* d_ws,
                              size_t ws_size, hipStream_t stream) {
  const float* X  = (const float*)d_in[0];
  const float* Wq = (const float*)d_in[2];
  const float* Wk = (const float*)d_in[3];
  const float* Wv = (const float*)d_in[4];
  const float* Wo = (const float*)d_in[5];
  float* out = (float*)d_out;

  char* ws = (char*)d_ws;
  uint16_t* Xbf = (uint16_t*)ws;                    // 16.78 MB [4096][2048]
  uint16_t* Wqk = (uint16_t*)(ws + 16777216);       // 16.78 MB [4096][2048]
  uint16_t* Qb  = (uint16_t*)(ws + 33554432);       // 16.78 MB [B,NH,S,HD]
  uint16_t* Kb  = (uint16_t*)(ws + 50331648);       // 16.78 MB [B,NH,S,HD]
  uint16_t* Wsm = (uint16_t*)(ws + 67108864);       //  8.39 MB (Wv bf16)
  uint16_t* Wob = (uint16_t*)(ws + 75497472);       //  8.39 MB (Wo bf16)
  uint16_t* Vtb = Wqk;   // Vt aliases Wqk (dead after QK GEMM)
  uint16_t* Ob  = Xbf;   // O aliases Xbf (dead after Vt GEMM)

  const float qscale = 0.125f;  // 1/sqrt(HD)

  hipFuncSetAttribute((const void*)gemm_qk,
                      hipFuncAttributeMaxDynamicSharedMemorySize, 98304);

  conv_batch<<<24576, 256, 0, stream>>>(X, Wq, Wk, Wv, Wo, Xbf, Wqk, Wsm, Wob);
  gemm_qk<<<256, 512, 98304, stream>>>(Xbf, Wqk, Qb, Kb, qscale);
  gemm_nt<1><<<dim3(32, 16), 256, 0, stream>>>(Wsm, Xbf, Vtb, 2048, 4096, 2048, 1.0f);
  attn_kernel<<<dim3(512), 256, 0, stream>>>(Qb, Kb, Vtb, Ob);
  gemm_nt<2><<<dim3(16, 32), 256, 0, stream>>>(Ob, Wob, out, 4096, 2048, 2048, 1.0f);
}

// Round 11
// 227.381 us; speedup vs baseline: 1.4395x; 1.0077x over previous
//
#include <hip/hip_runtime.h>
#include <hip/hip_bf16.h>
#include <stdint.h>

// Problem constants: B=2, S=2048, H=2048, NH=32, HD=64
#define S_LEN 2048
#define NHEAD 32
#define HDIM  64

using bf16x8 = __attribute__((ext_vector_type(8))) short;
using f32x4  = __attribute__((ext_vector_type(4))) float;
using f32x16 = __attribute__((ext_vector_type(16))) float;

__device__ __forceinline__ uint16_t f2bf(float f) {
  union { float f; uint32_t u; } c; c.f = f;
  uint32_t u = c.u;
  return (uint16_t)((u + 0x7FFFu + ((u >> 16) & 1u)) >> 16);
}

__device__ __forceinline__ void load_lds16(const void* g, void* l) {
  __builtin_amdgcn_global_load_lds(
      (const __attribute__((address_space(1))) void*)g,
      (__attribute__((address_space(3))) void*)l, 16, 0, 0);
}

__device__ __forceinline__ f32x16 mfma32(bf16x8 a, bf16x8 b, f32x16 c) {
  return __builtin_amdgcn_mfma_f32_32x32x16_bf16(a, b, c, 0, 0, 0);
}

__device__ __forceinline__ uint32_t cvtpk(float lo, float hi_) {
  uint32_t d;
  asm("v_cvt_pk_bf16_f32 %0, %1, %2" : "=v"(d) : "v"(lo), "v"(hi_));
  return d;
}
__device__ __forceinline__ void plswap(uint32_t& a, uint32_t& b) {
  asm volatile("v_permlane32_swap_b32 %0, %1" : "+v"(a), "+v"(b));
}
// 2^x directly (Q pre-scaled by log2e so 2^s == e^{s_true})
__device__ __forceinline__ float exp2_hw(float x) {
  float r;
  asm("v_exp_f32 %0, %1" : "=v"(r) : "v"(x));
  return r;
}

// ---------------- batched fp32 -> bf16 conversion (X + all 4 weights) -----
__global__ __launch_bounds__(256) void conv_batch(
    const float* __restrict__ X, const float* __restrict__ Wq,
    const float* __restrict__ Wk, const float* __restrict__ Wv,
    const float* __restrict__ Wo, uint16_t* __restrict__ Xbf,
    uint16_t* __restrict__ Wqk, uint16_t* __restrict__ Wvb,
    uint16_t* __restrict__ Wob) {
  int i = blockIdx.x * 256 + threadIdx.x;  // total 6291456
  const float* src; uint16_t* dst; int o;
  if (i < 2097152)      { src = X;  dst = Xbf;           o = i; }
  else if (i < 3145728) { src = Wq; dst = Wqk;           o = i - 2097152; }
  else if (i < 4194304) { src = Wk; dst = Wqk + 4194304; o = i - 3145728; }
  else if (i < 5242880) { src = Wv; dst = Wvb;           o = i - 4194304; }
  else                  { src = Wo; dst = Wob;           o = i - 5242880; }
  float4 v = ((const float4*)src)[o];
  uint64_t packed = (uint64_t)f2bf(v.x) | ((uint64_t)f2bf(v.y) << 16) |
                    ((uint64_t)f2bf(v.z) << 32) | ((uint64_t)f2bf(v.w) << 48);
  ((uint64_t*)dst)[o] = packed;
}

// ---------------- fused QK GEMM: 256x256, BK=32, 3-buf, 2-phase/tile ------
// (r6 — best measured 71.5 us / MfmaUtil ~39; family plateau ~950 TF)
__global__ __launch_bounds__(512, 2) void gemm_qk(
    const uint16_t* __restrict__ A, const uint16_t* __restrict__ Bw,
    uint16_t* __restrict__ Qo, uint16_t* __restrict__ Ko, float qscale) {
  extern __shared__ char smem[];  // 3 * 32768
  const int t = threadIdx.x;
  const int lane = t & 63, w = t >> 6;
  const int lrow = lane & 15, lgrp = lane >> 4;
  const int wr = w >> 2, wc = w & 3;
  const int id = blockIdx.x;
  const int swz = (id & 7) * 32 + (id >> 3);
  const int bm = (swz & 15) * 256, bn = (swz >> 4) * 256;
  constexpr int NT = 2048 / 32;

  const f32x4 zero4 = {0.f, 0.f, 0.f, 0.f};
  f32x4 acc[8][4];
#pragma unroll
  for (int mi = 0; mi < 8; ++mi)
#pragma unroll
    for (int ni = 0; ni < 4; ++ni) acc[mi][ni] = zero4;

  auto stage_mat = [&](const uint16_t* __restrict__ G, int grow0,
                       char* ldsbase, int kt) {
#pragma unroll
    for (int j = 0; j < 2; ++j) {
      const int s = t + j * 512;
      const int row = s >> 2;
      const int sc = (s & 3) ^ ((row >> 1) & 3);
      load_lds16(G + (size_t)(grow0 + row) * 2048 + kt + sc * 8,
                 ldsbase + j * 8192 + w * 1024);
    }
  };
  auto lda = [&](const char* Ab, int mi) -> bf16x8 {
    const int row = wr * 128 + mi * 16 + lrow;
    return *(const bf16x8*)(Ab + row * 64 + ((lgrp ^ ((row >> 1) & 3)) << 4));
  };
  auto ldb = [&](const char* Bb, int ni) -> bf16x8 {
    const int row = wc * 64 + ni * 16 + lrow;
    return *(const bf16x8*)(Bb + row * 64 + ((lgrp ^ ((row >> 1) & 3)) << 4));
  };

  stage_mat(A, bm, smem, 0);
  stage_mat(Bw, bn, smem + 16384, 0);
  stage_mat(A, bm, smem + 32768, 32);
  stage_mat(Bw, bn, smem + 32768 + 16384, 32);

  for (int kt = 0; kt < NT; ++kt) {
    char* cur = smem + (kt % 3) * 32768;
    char* nx2 = smem + ((kt + 2) % 3) * 32768;
    if (kt < NT - 1) asm volatile("s_waitcnt vmcnt(4)" ::: "memory");
    else             asm volatile("s_waitcnt vmcnt(0)" ::: "memory");
    __builtin_amdgcn_s_barrier();

    bf16x8 aF[4], bF[4];
#pragma unroll
    for (int mi = 0; mi < 4; ++mi) aF[mi] = lda(cur, mi);
#pragma unroll
    for (int ni = 0; ni < 4; ++ni) bF[ni] = ldb(cur + 16384, ni);
    if (kt + 2 < NT) stage_mat(A, bm, nx2, (kt + 2) * 32);
    __builtin_amdgcn_s_barrier();
    asm volatile("s_waitcnt lgkmcnt(0)" ::: "memory");
    __builtin_amdgcn_sched_barrier(0);
    __builtin_amdgcn_s_setprio(1);
#pragma unroll
    for (int mi = 0; mi < 4; ++mi)
#pragma unroll
      for (int ni = 0; ni < 4; ++ni)
        acc[mi][ni] = __builtin_amdgcn_mfma_f32_16x16x32_bf16(
            aF[mi], bF[ni], acc[mi][ni], 0, 0, 0);
    __builtin_amdgcn_s_setprio(0);
    __builtin_amdgcn_s_barrier();

    bf16x8 aG[4];
#pragma unroll
    for (int mi = 0; mi < 4; ++mi) aG[mi] = lda(cur, 4 + mi);
    if (kt + 2 < NT) stage_mat(Bw, bn, nx2 + 16384, (kt + 2) * 32);
    __builtin_amdgcn_s_barrier();
    asm volatile("s_waitcnt lgkmcnt(0)" ::: "memory");
    __builtin_amdgcn_sched_barrier(0);
    __builtin_amdgcn_s_setprio(1);
#pragma unroll
    for (int mi = 0; mi < 4; ++mi)
#pragma unroll
      for (int ni = 0; ni < 4; ++ni)
        acc[4 + mi][ni] = __builtin_amdgcn_mfma_f32_16x16x32_bf16(
            aG[mi], bF[ni], acc[4 + mi][ni], 0, 0, 0);
    __builtin_amdgcn_s_setprio(0);
  }

  const bool isQ = (bn < 2048);
#pragma unroll
  for (int mi = 0; mi < 8; ++mi) {
#pragma unroll
    for (int ni = 0; ni < 4; ++ni) {
      const int n = bn + wc * 64 + ni * 16 + lrow;
      const int n2 = isQ ? n : (n - 2048);
      const int h = n2 >> 6, d = n2 & 63;
#pragma unroll
      for (int r = 0; r < 4; ++r) {
        const int m = bm + wr * 128 + mi * 16 + lgrp * 4 + r;
        const int b = m >> 11, s = m & 2047;
        const size_t off = (((size_t)(b * NHEAD + h) * S_LEN + s) * HDIM) + d;
        if (isQ) Qo[off] = f2bf(acc[mi][ni][r] * qscale);
        else     Ko[off] = f2bf(acc[mi][ni][r]);
      }
    }
  }
}

// ---------------- NT GEMM 128^2, BK=32, 3-buf, 1 barrier/tile (r6) --------
template<int MODE>
__global__ __launch_bounds__(256, 3) void gemm_nt(
    const uint16_t* __restrict__ A, const uint16_t* __restrict__ B,
    void* __restrict__ C, int M, int N, int K, float scale) {
  __shared__ __align__(16) char smem[3][16384];

  const int t = threadIdx.x;
  const int lane = t & 63, w = t >> 6;
  const int lrow = lane & 15, lgrp = lane >> 4;
  const int bm = blockIdx.y * 128, bn = blockIdx.x * 128;
  const int wm = (w >> 1) * 64, wn = (w & 1) * 64;
  const int NT = K / 32;

  const f32x4 zero4 = {0.f, 0.f, 0.f, 0.f};
  f32x4 acc[4][4];
#pragma unroll
  for (int mi = 0; mi < 4; ++mi)
#pragma unroll
    for (int ni = 0; ni < 4; ++ni) acc[mi][ni] = zero4;

  auto stage_mat = [&](const uint16_t* __restrict__ G, int grow0,
                       char* ldsbase, int kt) {
#pragma unroll
    for (int j = 0; j < 2; ++j) {
      const int s = t + j * 256;
      const int row = s >> 2;
      const int sc = (s & 3) ^ ((row >> 1) & 3);
      load_lds16(G + (size_t)(grow0 + row) * K + kt + sc * 8,
                 ldsbase + j * 4096 + w * 1024);
    }
  };
  auto ldf = [&](const char* Mb, int base, int i) -> bf16x8 {
    const int row = base + i * 16 + lrow;
    return *(const bf16x8*)(Mb + row * 64 + ((lgrp ^ ((row >> 1) & 3)) << 4));
  };

  stage_mat(A, bm, smem[0], 0);
  stage_mat(B, bn, smem[0] + 8192, 0);
  stage_mat(A, bm, smem[1], 32);
  stage_mat(B, bn, smem[1] + 8192, 32);

  for (int kt = 0; kt < NT; ++kt) {
    char* cur = smem[kt % 3];
    if (kt < NT - 1) asm volatile("s_waitcnt vmcnt(4)" ::: "memory");
    else             asm volatile("s_waitcnt vmcnt(0)" ::: "memory");
    __builtin_amdgcn_s_barrier();

    if (kt + 2 < NT) {
      char* nx2 = smem[(kt + 2) % 3];
      stage_mat(A, bm, nx2, (kt + 2) * 32);
      stage_mat(B, bn, nx2 + 8192, (kt + 2) * 32);
    }

    bf16x8 aF[4], bF[4];
#pragma unroll
    for (int mi = 0; mi < 4; ++mi) aF[mi] = ldf(cur, wm, mi);
#pragma unroll
    for (int ni = 0; ni < 4; ++ni) bF[ni] = ldf(cur + 8192, wn, ni);
#pragma unroll
    for (int mi = 0; mi < 4; ++mi)
#pragma unroll
      for (int ni = 0; ni < 4; ++ni)
        acc[mi][ni] = __builtin_amdgcn_mfma_f32_16x16x32_bf16(
            aF[mi], bF[ni], acc[mi][ni], 0, 0, 0);
  }

#pragma unroll
  for (int mi = 0; mi < 4; ++mi) {
#pragma unroll
    for (int ni = 0; ni < 4; ++ni) {
      const int n = bn + wn + ni * 16 + lrow;
#pragma unroll
      for (int r = 0; r < 4; ++r) {
        const int m = bm + wm + mi * 16 + lgrp * 4 + r;
        const float v = acc[mi][ni][r] * scale;
        if (MODE == 2) {
          ((float*)C)[(size_t)m * N + n] = v;
        } else {
          const int h = m >> 6, d = m & 63;
          const int b = n >> 11, s = n & 2047;
          ((uint16_t*)C)[(((size_t)(b * NHEAD + h) * HDIM + d) * S_LEN) + s] =
              f2bf(v);
        }
      }
    }
  }
}

// ---------------- causal flash attention v4b: r4 structure + exp2 softmax -
// Q pre-scaled by log2(e)/8 so weights are 2^s = e^{s_true}; v_exp_f32
// directly (no per-element mul). Otherwise byte-identical to the proven r4.
__global__ __launch_bounds__(256, 3) void attn_kernel(
    const uint16_t* __restrict__ Q, const uint16_t* __restrict__ K,
    const uint16_t* __restrict__ Vt, uint16_t* __restrict__ O) {
  __shared__ __align__(16) uint16_t Ks[2][64 * 64];
  __shared__ __align__(16) uint16_t Vs[2][64 * 64];
  __shared__ float Ls[4][32];

  const int t = threadIdx.x, lane = t & 63, w = t >> 6;
  const int qcol = lane & 31, hi = lane >> 5;
  const int id = blockIdx.x;
  const int bh = (id & 7) * 8 + ((id >> 3) & 7);  // 8 heads per XCD
  const int p = id >> 6;                           // 0..7
  const int b = bh >> 5, h = bh & 31;

  const uint16_t* Qbh = Q + (size_t)bh * S_LEN * HDIM;
  const uint16_t* Kbh = K + (size_t)bh * S_LEN * HDIM;
  const uint16_t* Vbh = Vt + (size_t)bh * HDIM * S_LEN;

  const int srow = lane >> 3;
  const int schunk = (lane & 7) ^ srow;

  auto stage = [&](int k0, int bi) {
#pragma unroll
    for (int j = 0; j < 2; ++j) {
      const int r = j * 32 + w * 8 + srow;
      load_lds16(Kbh + (size_t)(k0 + r) * HDIM + schunk * 8,
                 (char*)&Ks[bi][0] + j * 4096 + w * 1024);
      load_lds16(Vbh + (size_t)r * S_LEN + k0 + schunk * 8,
                 (char*)&Vs[bi][0] + j * 4096 + w * 1024);
    }
  };

  for (int pass = 0; pass < 2; ++pass) {
    const int jq = pass ? (15 - p) : p;
    const int qw = jq * 128 + w * 32;
    const int qg = qw + qcol;

    bf16x8 qB[4];
    {
      const uint16_t* qp = Qbh + (size_t)(qw + qcol) * HDIM + hi * 8;
#pragma unroll
      for (int j = 0; j < 4; ++j) qB[j] = *(const bf16x8*)(qp + 16 * j);
    }

    f32x16 oacc0, oacc1;
#pragma unroll
    for (int r = 0; r < 16; ++r) { oacc0[r] = 0.f; oacc1[r] = 0.f; }
    float lsum = 0.f;

    const int nt = 2 * jq + 2;
    for (int kt = 0; kt < nt; ++kt) {
      const int cur = kt & 1;
      const int k0 = kt * 64;
      if (kt == 0) { __syncthreads(); stage(0, 0); }
      __syncthreads();
      if (kt + 1 < nt) stage((kt + 1) * 64, cur ^ 1);

      if (k0 <= qw + 31) {
        const char* Kc = (const char*)&Ks[cur][0];
        const char* Vc = (const char*)&Vs[cur][0];

        f32x16 s0, s1;
#pragma unroll
        for (int r = 0; r < 16; ++r) { s0[r] = 0.f; s1[r] = 0.f; }
        const int rk0 = qcol, rk1 = 32 + qcol;
        const int x0 = rk0 & 7;
        __builtin_amdgcn_s_setprio(1);
#pragma unroll
        for (int j = 0; j < 4; ++j) {
          bf16x8 kf0 = *(const bf16x8*)(Kc + rk0 * 128 + (((2*j+hi) ^ x0) << 4));
          bf16x8 kf1 = *(const bf16x8*)(Kc + rk1 * 128 + (((2*j+hi) ^ x0) << 4));
          s0 = mfma32(kf0, qB[j], s0);
          s1 = mfma32(kf1, qB[j], s1);
        }
        __builtin_amdgcn_s_setprio(0);

        if (k0 + 63 > qw) {
#pragma unroll
          for (int r = 0; r < 16; ++r) {
            const int krow = (r & 3) + 8 * (r >> 2) + 4 * hi;
            s0[r] = (k0 + krow <= qg) ? exp2_hw(s0[r]) : 0.f;
            s1[r] = (k0 + 32 + krow <= qg) ? exp2_hw(s1[r]) : 0.f;
            lsum += s0[r] + s1[r];
          }
        } else {
#pragma unroll
          for (int r = 0; r < 16; ++r) {
            s0[r] = exp2_hw(s0[r]);
            s1[r] = exp2_hw(s1[r]);
            lsum += s0[r] + s1[r];
          }
        }

        bf16x8 paf[4];
#pragma unroll
        for (int tt = 0; tt < 4; ++tt) {
          const int o = 8 * (tt & 1);
          uint32_t a0, a1, a2, a3;
          if (tt < 2) {
            a0 = cvtpk(s0[o + 0], s0[o + 1]);
            a1 = cvtpk(s0[o + 2], s0[o + 3]);
            a2 = cvtpk(s0[o + 4], s0[o + 5]);
            a3 = cvtpk(s0[o + 6], s0[o + 7]);
          } else {
            a0 = cvtpk(s1[o + 0], s1[o + 1]);
            a1 = cvtpk(s1[o + 2], s1[o + 3]);
            a2 = cvtpk(s1[o + 4], s1[o + 5]);
            a3 = cvtpk(s1[o + 6], s1[o + 7]);
          }
          plswap(a0, a2);
          plswap(a1, a3);
          union { uint32_t u[4]; bf16x8 v; } pk;
          pk.u[0] = a0; pk.u[1] = a1; pk.u[2] = a2; pk.u[3] = a3;
          paf[tt] = pk.v;
        }

        __builtin_amdgcn_s_setprio(1);
#pragma unroll
        for (int tt = 0; tt < 4; ++tt) {
          const int c = 2 * tt + hi;
          bf16x8 v0f = *(const bf16x8*)(Vc + rk0 * 128 + ((c ^ x0) << 4));
          bf16x8 v1f = *(const bf16x8*)(Vc + rk1 * 128 + ((c ^ x0) << 4));
          oacc0 = mfma32(paf[tt], v0f, oacc0);
          oacc1 = mfma32(paf[tt], v1f, oacc1);
        }
        __builtin_amdgcn_s_setprio(0);
      }
    }

    lsum += __shfl_xor(lsum, 32, 64);
    if (hi == 0) Ls[w][qcol] = 1.0f / lsum;

#pragma unroll
    for (int r = 0; r < 16; ++r) {
      const int qrow = (r & 3) + 8 * (r >> 2) + 4 * hi;
      const float inv = Ls[w][qrow];
      const size_t base = ((size_t)b * S_LEN + qw + qrow) * 2048 + h * 64;
      O[base + qcol] = f2bf(oacc0[r] * inv);
      O[base + 32 + qcol] = f2bf(oacc1[r] * inv);
    }
  }
}

// ---------------- launcher ----------------
extern "C" void kernel_launch(void* const* d_in, const int* in_sizes, int n_in,
                              void* d_out, int out_size, void* d_ws,
                              size_t ws_size, hipStream_t stream) {
  const float* X  = (const float*)d_in[0];
  const float* Wq = (const float*)d_in[2];
  const float* Wk = (const float*)d_in[3];
  const float* Wv = (const float*)d_in[4];
  const float* Wo = (const float*)d_in[5];
  float* out = (float*)d_out;

  char* ws = (char*)d_ws;
  uint16_t* Xbf = (uint16_t*)ws;                    // 16.78 MB [4096][2048]
  uint16_t* Wqk = (uint16_t*)(ws + 16777216);       // 16.78 MB [4096][2048]
  uint16_t* Qb  = (uint16_t*)(ws + 33554432);       // 16.78 MB [B,NH,S,HD]
  uint16_t* Kb  = (uint16_t*)(ws + 50331648);       // 16.78 MB [B,NH,S,HD]
  uint16_t* Wsm = (uint16_t*)(ws + 67108864);       //  8.39 MB (Wv bf16)
  uint16_t* Wob = (uint16_t*)(ws + 75497472);       //  8.39 MB (Wo bf16)
  uint16_t* Vtb = Wqk;   // Vt aliases Wqk (dead after QK GEMM)
  uint16_t* Ob  = Xbf;   // O aliases Xbf (dead after Vt GEMM)

  // 1/sqrt(HD) * log2(e): softmax weights computed as 2^s (v_exp_f32 direct)
  const float qscale = 0.125f * 1.4426950408889634f;

  hipFuncSetAttribute((const void*)gemm_qk,
                      hipFuncAttributeMaxDynamicSharedMemorySize, 98304);

  conv_batch<<<24576, 256, 0, stream>>>(X, Wq, Wk, Wv, Wo, Xbf, Wqk, Wsm, Wob);
  gemm_qk<<<256, 512, 98304, stream>>>(Xbf, Wqk, Qb, Kb, qscale);
  gemm_nt<1><<<dim3(32, 16), 256, 0, stream>>>(Wsm, Xbf, Vtb, 2048, 4096, 2048, 1.0f);
  attn_kernel<<<dim3(512), 256, 0, stream>>>(Qb, Kb, Vtb, Ob);
  gemm_nt<2><<<dim3(16, 32), 256, 0, stream>>>(Ob, Wob, out, 4096, 2048, 2048, 1.0f);
}